// Round 2
// baseline (493.866 us; speedup 1.0000x reference)
//
#include <hip/hip_runtime.h>
#include <hip/hip_bf16.h>
#include <cstdint>

typedef unsigned short u16;
typedef short s16x8 __attribute__((ext_vector_type(8)));
typedef short s16x4 __attribute__((ext_vector_type(4)));
typedef float f32x4 __attribute__((ext_vector_type(4)));

#define C_DIM 384
#define NHEAD 12
#define HD    32
#define NTOK  343     // tokens per window (7^3)
#define NWIN  64
#define LTOT  21952   // 28^3
#define SIDE  28

__device__ __forceinline__ float u2f(u16 u) {
    return __uint_as_float(((unsigned int)u) << 16);
}
__device__ __forceinline__ u16 f2b(float f) {
    unsigned int u = __float_as_uint(f);
    return (u16)((u + 0x7fffu + ((u >> 16) & 1u)) >> 16);   // RNE
}
__device__ __forceinline__ float exp2_hw(float x) {
    float r;
    asm("v_exp_f32 %0, %1" : "=v"(r) : "v"(x));
    return r;
}
// pack two f32 -> two bf16 (RNE) in one op
__device__ __forceinline__ unsigned int pk_bf16(float lo, float hi) {
    unsigned int r;
    asm("v_cvt_pk_bf16_f32 %0, %1, %2" : "=v"(r) : "v"(lo), "v"(hi));
    return r;
}
// gelu tanh-approx: 0.5x(1+tanh(z)) == x / (1 + 2^(-2z*log2e))
__device__ __forceinline__ float gelu_fast(float x) {
    float e = exp2_hw(-2.3022083f * (x + 0.044715f * x * x * x));
    return x * __builtin_amdgcn_rcpf(1.f + e);
}

// ---------------------------------------------------------------------------
// Weight transpose + f32->bf16: Wt[n][k] = bf16(W[k][n]).  W is KxN row-major.
// ---------------------------------------------------------------------------
__global__ __launch_bounds__(256) void k_wt(
    const float* __restrict__ W, u16* __restrict__ Wt, int K, int N)
{
    __shared__ float T[64][65];
    int k0 = blockIdx.x * 64, n0 = blockIdx.y * 64;
    int t = threadIdx.x;
    int c = t & 63, rg = t >> 6;
#pragma unroll
    for (int i = 0; i < 16; i++) {
        int r = rg * 16 + i;
        T[r][c] = W[(size_t)(k0 + r) * N + n0 + c];
    }
    __syncthreads();
    int k = t & 63, ng = t >> 6;
#pragma unroll
    for (int i = 0; i < 16; i++) {
        int n = ng * 16 + i;
        Wt[(size_t)(n0 + n) * K + k0 + k] = f2b(T[k][n]);
    }
}

// Same, but the k (contraction) index is pi-permuted within each 128-block:
// j = k%128 = ct*16+n  ->  j' = 32*(ct>>1) + 2*n + (ct&1).
// Used for w2 so mlp1 can store h1 in pair-packed column order.
__global__ __launch_bounds__(256) void k_wt_pi(
    const float* __restrict__ W, u16* __restrict__ Wt, int K, int N)
{
    __shared__ float T[64][65];
    int k0 = blockIdx.x * 64, n0 = blockIdx.y * 64;
    int t = threadIdx.x;
    int c = t & 63, rg = t >> 6;
#pragma unroll
    for (int i = 0; i < 16; i++) {
        int r = rg * 16 + i;
        T[r][c] = W[(size_t)(k0 + r) * N + n0 + c];
    }
    __syncthreads();
    int k = t & 63, ng = t >> 6;
    int kg = k0 + k;
    int j = kg & 127, ct = j >> 4, nn = j & 15;
    int kp = (kg & ~127) | ((ct >> 1) << 5) | (nn << 1) | (ct & 1);
#pragma unroll
    for (int i = 0; i < 16; i++) {
        int n = ng * 16 + i;
        Wt[(size_t)(n0 + n) * K + kp] = f2b(T[k][n]);
    }
}

// ---------------------------------------------------------------------------
// Kernel 1: dual LayerNorm + window partition -> bf16; also res = bf16(skip+xup)
// ---------------------------------------------------------------------------
__global__ __launch_bounds__(256) void k_lnprep(
    const float* __restrict__ skip, const float* __restrict__ xup,
    const float* __restrict__ g, const float* __restrict__ bta,
    u16* __restrict__ skW, u16* __restrict__ qW, u16* __restrict__ res)
{
    int t = blockIdx.x * 4 + (threadIdx.x >> 6);
    int lane = threadIdx.x & 63;
    const float* ps = skip + (size_t)t * C_DIM;
    const float* px = xup + (size_t)t * C_DIM;
    float vs[6], vx[6];
    float s1 = 0.f, s2 = 0.f, x1 = 0.f, x2 = 0.f;
#pragma unroll
    for (int j = 0; j < 6; j++) {
        float a = ps[lane + j * 64];
        float b = px[lane + j * 64];
        vs[j] = a; vx[j] = b;
        s1 += a; s2 += a * a; x1 += b; x2 += b * b;
    }
#pragma unroll
    for (int off = 32; off; off >>= 1) {
        s1 += __shfl_xor(s1, off);
        s2 += __shfl_xor(s2, off);
        x1 += __shfl_xor(x1, off);
        x2 += __shfl_xor(x2, off);
    }
    float ms = s1 * (1.f / 384.f), mx = x1 * (1.f / 384.f);
    float rs = rsqrtf(fmaxf(s2 * (1.f / 384.f) - ms * ms, 0.f) + 1e-5f);
    float rx = rsqrtf(fmaxf(x2 * (1.f / 384.f) - mx * mx, 0.f) + 1e-5f);
    int d = t / 784, rem = t % 784, hh = rem / 28, ww = rem % 28;
    int win = (d / 7) * 16 + (hh / 7) * 4 + (ww / 7);
    int n = (d % 7) * 49 + (hh % 7) * 7 + (ww % 7);
    size_t dst = ((size_t)(win * NTOK + n)) * C_DIM + lane;
    size_t td  = (size_t)t * C_DIM + lane;
#pragma unroll
    for (int j = 0; j < 6; j++) {
        int c = lane + j * 64;
        float gg = g[c], bb = bta[c];
        skW[dst + j * 64] = f2b((vs[j] - ms) * rs * gg + bb);
        qW[dst + j * 64]  = f2b((vx[j] - mx) * rx * gg + bb);
        res[td + j * 64]  = f2b(vs[j] + vx[j]);
    }
}

// ---------------------------------------------------------------------------
// Kernel 5: LayerNorm of x2 (bf16) -> lnx (bf16).
// ---------------------------------------------------------------------------
__global__ __launch_bounds__(256) void k_ln2(
    const u16* __restrict__ x2, const float* __restrict__ g,
    const float* __restrict__ bta, u16* __restrict__ lnx)
{
    int t = blockIdx.x * 4 + (threadIdx.x >> 6);
    int lane = threadIdx.x & 63;
    const u16* p = x2 + (size_t)t * C_DIM;
    float v[6];
    float s1 = 0.f, s2 = 0.f;
#pragma unroll
    for (int j = 0; j < 6; j++) {
        float a = u2f(p[lane + j * 64]);
        v[j] = a; s1 += a; s2 += a * a;
    }
#pragma unroll
    for (int off = 32; off; off >>= 1) {
        s1 += __shfl_xor(s1, off);
        s2 += __shfl_xor(s2, off);
    }
    float m = s1 * (1.f / 384.f);
    float r = rsqrtf(fmaxf(s2 * (1.f / 384.f) - m * m, 0.f) + 1e-5f);
    size_t dst = (size_t)t * C_DIM + lane;
#pragma unroll
    for (int j = 0; j < 6; j++) {
        int c = lane + j * 64;
        lnx[dst + j * 64] = f2b((v[j] - m) * r * g[c] + bta[c]);
    }
}

// ---------------------------------------------------------------------------
// 128x128 MFMA GEMM core (unchanged).
// ---------------------------------------------------------------------------
#define BPAD 40   // LDS row stride in u16 (32 data + 8 pad; 2-way banks)

__device__ __forceinline__ void gemm128(
    const u16* __restrict__ A, const u16* __restrict__ Bt, int K, int M,
    int rowBase, int colBase, int tid,
    u16 (*As)[BPAD], u16 (*Bs)[BPAD], f32x4 acc[2][8])
{
    const int sr  = tid >> 2;
    const int scg = (tid & 3) << 3;
    const int lane = tid & 63, wv = tid >> 6;
    const int m16 = lane & 15, quad = lane >> 4;

    int ra0 = min(rowBase + sr, M - 1);
    int ra1 = min(rowBase + 64 + sr, M - 1);
    const u16* pa0 = A + (size_t)ra0 * K + scg;
    const u16* pa1 = A + (size_t)ra1 * K + scg;
    const u16* pb0 = Bt + (size_t)(colBase + sr) * K + scg;
    const u16* pb1 = Bt + (size_t)(colBase + 64 + sr) * K + scg;

    uint4 a0 = *(const uint4*)pa0, a1 = *(const uint4*)pa1;
    uint4 b0 = *(const uint4*)pb0, b1 = *(const uint4*)pb1;

    for (int kk = 0; kk < K; kk += 32) {
        *(uint4*)&As[sr][scg]      = a0;
        *(uint4*)&As[64 + sr][scg] = a1;
        *(uint4*)&Bs[sr][scg]      = b0;
        *(uint4*)&Bs[64 + sr][scg] = b1;
        __syncthreads();
        if (kk + 32 < K) {
            a0 = *(const uint4*)(pa0 + kk + 32);
            a1 = *(const uint4*)(pa1 + kk + 32);
            b0 = *(const uint4*)(pb0 + kk + 32);
            b1 = *(const uint4*)(pb1 + kk + 32);
        }
        s16x8 af0 = *(const s16x8*)&As[wv * 32 + m16][quad * 8];
        s16x8 af1 = *(const s16x8*)&As[wv * 32 + 16 + m16][quad * 8];
#pragma unroll
        for (int c = 0; c < 8; c++) {
            s16x8 bf = *(const s16x8*)&Bs[c * 16 + m16][quad * 8];
            acc[0][c] = __builtin_amdgcn_mfma_f32_16x16x32_bf16(af0, bf, acc[0][c], 0, 0, 0);
            acc[1][c] = __builtin_amdgcn_mfma_f32_16x16x32_bf16(af1, bf, acc[1][c], 0, 0, 0);
        }
        __syncthreads();
    }
}

// ---------------------------------------------------------------------------
// 64x128 MFMA GEMM core with 2-deep register prefetch (unchanged).
// ---------------------------------------------------------------------------
__device__ __forceinline__ void gemm64_d2(
    const u16* __restrict__ A, const u16* __restrict__ Bt, int K, int M,
    int rowBase, int colBase, int tid,
    u16 (*As)[BPAD], u16 (*Bs)[BPAD], f32x4 acc[8])
{
    const int sr  = tid >> 2;
    const int scg = (tid & 3) << 3;
    const int lane = tid & 63, wv = tid >> 6;
    const int m16 = lane & 15, quad = lane >> 4;

    int ra = min(rowBase + sr, M - 1);
    const u16* pa  = A + (size_t)ra * K + scg;
    const u16* pb0 = Bt + (size_t)(colBase + sr) * K + scg;
    const u16* pb1 = Bt + (size_t)(colBase + 64 + sr) * K + scg;

    uint4 a0  = *(const uint4*)pa;
    uint4 b00 = *(const uint4*)pb0;
    uint4 b01 = *(const uint4*)pb1;
    uint4 a1  = *(const uint4*)(pa + 32);
    uint4 b10 = *(const uint4*)(pb0 + 32);
    uint4 b11 = *(const uint4*)(pb1 + 32);

    for (int kk = 0; kk < K; kk += 64) {
        *(uint4*)&As[sr][scg]      = a0;
        *(uint4*)&Bs[sr][scg]      = b00;
        *(uint4*)&Bs[64 + sr][scg] = b01;
        __syncthreads();
        if (kk + 64 < K) {
            a0  = *(const uint4*)(pa  + kk + 64);
            b00 = *(const uint4*)(pb0 + kk + 64);
            b01 = *(const uint4*)(pb1 + kk + 64);
        }
        {
            s16x8 af = *(const s16x8*)&As[wv * 16 + m16][quad * 8];
#pragma unroll
            for (int c = 0; c < 8; c++) {
                s16x8 bf = *(const s16x8*)&Bs[c * 16 + m16][quad * 8];
                acc[c] = __builtin_amdgcn_mfma_f32_16x16x32_bf16(af, bf, acc[c], 0, 0, 0);
            }
        }
        __syncthreads();
        *(uint4*)&As[sr][scg]      = a1;
        *(uint4*)&Bs[sr][scg]      = b10;
        *(uint4*)&Bs[64 + sr][scg] = b11;
        __syncthreads();
        if (kk + 96 < K) {
            a1  = *(const uint4*)(pa  + kk + 96);
            b10 = *(const uint4*)(pb0 + kk + 96);
            b11 = *(const uint4*)(pb1 + kk + 96);
        }
        {
            s16x8 af = *(const s16x8*)&As[wv * 16 + m16][quad * 8];
#pragma unroll
            for (int c = 0; c < 8; c++) {
                s16x8 bf = *(const s16x8*)&Bs[c * 16 + m16][quad * 8];
                acc[c] = __builtin_amdgcn_mfma_f32_16x16x32_bf16(af, bf, acc[c], 0, 0, 0);
            }
        }
        __syncthreads();
    }
}

#define EPI_SETUP \
    int lane = tid & 63, wv = tid >> 6, quad = lane >> 4, n16 = lane & 15;

// KV projection (K=384, N=768): scatter to K/V (w,head,n,d) bf16.
__global__ __launch_bounds__(256) void k_gemm_kv(
    const u16* __restrict__ A, const u16* __restrict__ Wt, const float* __restrict__ bias,
    u16* __restrict__ Kb, u16* __restrict__ Vb)
{
    __shared__ __align__(16) u16 As[128][BPAD];
    __shared__ __align__(16) u16 Bs[128][BPAD];
    f32x4 acc[2][8] = {};
    int tid = threadIdx.x;
    int rowBase = blockIdx.x * 128, colBase = blockIdx.y * 128;
    gemm128(A, Wt, 384, LTOT, rowBase, colBase, tid, As, Bs, acc);
    EPI_SETUP
#pragma unroll
    for (int c = 0; c < 8; c++) {
        int col = colBase + c * 16 + n16;
        float bcol = bias[col];
        int isv = col >= 384;
        int remc = col - (isv ? 384 : 0);
        int hh = remc >> 5, dd = remc & 31;
#pragma unroll
        for (int rt = 0; rt < 2; rt++)
#pragma unroll
        for (int reg = 0; reg < 4; reg++) {
            int r = rowBase + wv * 32 + rt * 16 + quad * 4 + reg;
            if (r < LTOT) {
                int w = r / NTOK, nn = r % NTOK;
                size_t dst = ((size_t)((w * NHEAD + hh) * NTOK + nn)) * HD + dd;
                (isv ? Vb : Kb)[dst] = f2b(acc[rt][c][reg] + bcol);
            }
        }
    }
}

// Output projection (K=384, N=384) + bias + residual res (bf16) -> x2 bf16.
__global__ __launch_bounds__(256) void k_gemm_proj(
    const u16* __restrict__ A, const u16* __restrict__ Wt, const float* __restrict__ bias,
    const u16* __restrict__ res, u16* __restrict__ x2)
{
    __shared__ __align__(16) u16 As[64][BPAD];
    __shared__ __align__(16) u16 Bs[128][BPAD];
    f32x4 acc[8] = {};
    int tid = threadIdx.x;
    int rowBase = blockIdx.x * 64, colBase = blockIdx.y * 128;
    gemm64_d2(A, Wt, 384, LTOT, rowBase, colBase, tid, As, Bs, acc);
    EPI_SETUP
#pragma unroll
    for (int c = 0; c < 8; c++) {
        int col = colBase + c * 16 + n16;
        float bcol = bias[col];
#pragma unroll
        for (int reg = 0; reg < 4; reg++) {
            int r = rowBase + wv * 16 + quad * 4 + reg;
            if (r < LTOT) {
                size_t idx = (size_t)r * C_DIM + col;
                x2[idx] = f2b(acc[c][reg] + bcol + u2f(res[idx]));
            }
        }
    }
}

// MLP1 (K=384, N=1536) + bias + gelu -> h1 chunk bf16, pair-packed columns:
// within each 128-col block, cols (32p+n, 32p+16+n) -> packed u32 at 32p+2n.
// w2t is permuted identically (k_wt_pi) so mlp2 is unchanged.
__global__ __launch_bounds__(256) void k_gemm_mlp1(
    const u16* __restrict__ A, const u16* __restrict__ Wt, const float* __restrict__ bias,
    u16* __restrict__ h1c, int rowOfs)
{
    __shared__ __align__(16) u16 As[128][BPAD];
    __shared__ __align__(16) u16 Bs[128][BPAD];
    f32x4 acc[2][8] = {};
    int tid = threadIdx.x;
    int rowBase = rowOfs + blockIdx.x * 128, colBase = blockIdx.y * 128;
    gemm128(A, Wt, 384, LTOT, rowBase, colBase, tid, As, Bs, acc);
    EPI_SETUP
#pragma unroll
    for (int p = 0; p < 4; p++) {
        int col0 = colBase + p * 32 + n16;    // ct = 2p
        int col1 = col0 + 16;                 // ct = 2p+1
        float bc0 = bias[col0], bc1 = bias[col1];
        int dcol = colBase + p * 32 + 2 * n16;
#pragma unroll
        for (int rt = 0; rt < 2; rt++)
#pragma unroll
        for (int reg = 0; reg < 4; reg++) {
            int r = rowBase + wv * 32 + rt * 16 + quad * 4 + reg;
            if (r < LTOT) {
                size_t rl = (size_t)(r - rowOfs);
                float v0 = gelu_fast(acc[rt][2 * p][reg] + bc0);
                float v1 = gelu_fast(acc[rt][2 * p + 1][reg] + bc1);
                *(unsigned int*)&h1c[rl * 1536 + dcol] = pk_bf16(v0, v1);
            }
        }
    }
}

// MLP2 (K=1536 permuted, N=384) + bias + residual x2 (bf16) -> out f32 (final).
__global__ __launch_bounds__(256) void k_gemm_mlp2(
    const u16* __restrict__ A, const u16* __restrict__ Wt, const float* __restrict__ bias,
    const u16* __restrict__ x2, float* __restrict__ out, int rowOfs, int chunkRows)
{
    __shared__ __align__(16) u16 As[64][BPAD];
    __shared__ __align__(16) u16 Bs[128][BPAD];
    f32x4 acc[8] = {};
    int tid = threadIdx.x;
    int rowBase = blockIdx.x * 64, colBase = blockIdx.y * 128;   // local rows
    gemm64_d2(A, Wt, 1536, chunkRows, rowBase, colBase, tid, As, Bs, acc);
    EPI_SETUP
#pragma unroll
    for (int c = 0; c < 8; c++) {
        int col = colBase + c * 16 + n16;
        float bcol = bias[col];
#pragma unroll
        for (int reg = 0; reg < 4; reg++) {
            int rl = rowBase + wv * 16 + quad * 4 + reg;
            int rg = rowOfs + rl;
            if (rl < chunkRows && rg < LTOT) {
                size_t idx = (size_t)rg * C_DIM + col;
                out[idx] = acc[c][reg] + bcol + u2f(x2[idx]);
            }
        }
    }
}

// ---------------------------------------------------------------------------
// Kernel 3: MFMA flash attention, merged halves: one 512-thread block per
// (head, window); 8 waves, each owns ~3 of 22 q-tiles. K/V staged once.
// Softmax in log2 domain (scale & bias pre-multiplied by log2e) -> bare
// v_exp_f32. P stored pair-packed (col c = 2*(k&15)+(k>>4)) via
// v_cvt_pk_bf16_f32 + ds_write_b32; V staged with the identical column
// permutation so P.V is unchanged.
// LDS: Ks 28160 + Vt 23040 + rp16 4400 + code 704 + Pb 9216 = 65520 B.
// ---------------------------------------------------------------------------
#define KP  40     // Ks row stride (u16), 80 B: 16B-aligned b128 rows
#define VP  360    // Vt row stride (u16), 720 B: 16B-aligned, 8-bank spread
#define PBS 36     // Pb row stride (u16), 72 B: 8B-aligned (read as 2xb64)

__global__ __launch_bounds__(512, 4) void k_attn(
    const u16* __restrict__ qW, const u16* __restrict__ Kb, const u16* __restrict__ Vb,
    const float* __restrict__ rpb, u16* __restrict__ oT)
{
    __shared__ __align__(16) u16 Ks[352 * KP];       // 28160 B
    __shared__ __align__(16) u16 Vt[32 * VP];        // 23040 B
    __shared__ __align__(16) u16 rp16[2200];         //  4400 B
    __shared__ __align__(16) u16 code[352];          //   704 B
    __shared__ __align__(16) u16 Pb[8 * 16 * PBS];   //  9216 B

    const int h = blockIdx.x, w = blockIdx.y;
    const int tid = threadIdx.x;
    const int lane = tid & 63, wv = tid >> 6;
    const int m16 = lane & 15, quad = lane >> 4;
    const size_t base = ((size_t)(w * NHEAD + h)) * NTOK * HD;

    // K: rows = tokens (zero-padded to 352), 16B chunks.
    for (int t = tid; t < 1408; t += 512) {
        int r = t >> 2, c = (t & 3) << 3;
        uint4 u = make_uint4(0, 0, 0, 0);
        if (r < NTOK) u = *(const uint4*)(Kb + base + r * HD + c);
        *(uint4*)&Ks[r * KP + c] = u;
    }
    // V transposed [d][col], col = 32*kb + 2*j (token kb*32+j) | +1 (token +16).
    for (int t = tid; t < 704; t += 512) {
        int dg = t / 176, rem = t - dg * 176;
        int kb = rem >> 4, j = rem & 15;
        int n0 = kb * 32 + j, n1 = n0 + 16;
        uint4 uA = make_uint4(0, 0, 0, 0), uB = make_uint4(0, 0, 0, 0);
        if (n0 < NTOK) uA = *(const uint4*)(Vb + base + n0 * HD + dg * 8);
        if (n1 < NTOK) uB = *(const uint4*)(Vb + base + n1 * HD + dg * 8);
        int d0 = dg * 8, colu = kb * 32 + 2 * j;
        unsigned int pk0 = (uA.x & 0xffffu) | (uB.x << 16);
        unsigned int pk1 = (uA.x >> 16)     | (uB.x & 0xffff0000u);
        unsigned int pk2 = (uA.y & 0xffffu) | (uB.y << 16);
        unsigned int pk3 = (uA.y >> 16)     | (uB.y & 0xffff0000u);
        unsigned int pk4 = (uA.z & 0xffffu) | (uB.z << 16);
        unsigned int pk5 = (uA.z >> 16)     | (uB.z & 0xffff0000u);
        unsigned int pk6 = (uA.w & 0xffffu) | (uB.w << 16);
        unsigned int pk7 = (uA.w >> 16)     | (uB.w & 0xffff0000u);
        *(unsigned int*)&Vt[(d0 + 0) * VP + colu] = pk0;
        *(unsigned int*)&Vt[(d0 + 1) * VP + colu] = pk1;
        *(unsigned int*)&Vt[(d0 + 2) * VP + colu] = pk2;
        *(unsigned int*)&Vt[(d0 + 3) * VP + colu] = pk3;
        *(unsigned int*)&Vt[(d0 + 4) * VP + colu] = pk4;
        *(unsigned int*)&Vt[(d0 + 5) * VP + colu] = pk5;
        *(unsigned int*)&Vt[(d0 + 6) * VP + colu] = pk6;
        *(unsigned int*)&Vt[(d0 + 7) * VP + colu] = pk7;
    }
    // bias table in log2 units
    for (int t = tid; t < 2200; t += 512)
        rp16[t] = (t < 2197) ? f2b(rpb[t * NHEAD + h] * 1.4426950408889634f) : (u16)0;
    for (int t = tid; t < 352; t += 512) {
        int z = t / 49, rem = t % 49, y = rem / 7, x = rem % 7;
        code[t] = (t < NTOK) ? (u16)(z * 169 + y * 13 + x) : (u16)1098;
    }
    __syncthreads();

    const float scale = 0.2550348772f;  // (1/sqrt(32)) * log2(e)
    u16* myP = Pb + wv * 16 * PBS;

    for (int qt = wv; qt < 22; qt += 8) {
        int qbase = qt * 16;
        int qrow = min(qbase + m16, NTOK - 1);
        s16x8 qf = *(const s16x8*)(qW + ((size_t)(w * NTOK + qrow)) * C_DIM
                                       + h * HD + quad * 8);
        int qcv[4];
#pragma unroll
        for (int i = 0; i < 4; i++) qcv[i] = code[qbase + quad * 4 + i];

        f32x4 S0[11], S1[11];
        float mx[4] = {-1e30f, -1e30f, -1e30f, -1e30f};

#pragma unroll
        for (int ks = 0; ks < 11; ks++) {
            int kbase = ks * 32;
            int kt0 = kbase + m16, kt1 = kt0 + 16;
            s16x8 kf0 = *(const s16x8*)&Ks[kt0 * KP + quad * 8];
            s16x8 kf1 = *(const s16x8*)&Ks[kt1 * KP + quad * 8];
            f32x4 z = {0.f, 0.f, 0.f, 0.f};
            f32x4 sA = __builtin_amdgcn_mfma_f32_16x16x32_bf16(qf, kf0, z, 0, 0, 0);
            f32x4 sB = __builtin_amdgcn_mfma_f32_16x16x32_bf16(qf, kf1, z, 0, 0, 0);
            int kc0 = code[kt0], kc1 = code[kt1];
            bool k1ok = (ks < 10) || (kt1 < NTOK);
#pragma unroll
            for (int i = 0; i < 4; i++) {
                float b0 = u2f(rp16[qcv[i] - kc0 + 1098]);
                float b1 = u2f(rp16[qcv[i] - kc1 + 1098]);
                float sa = fmaf(sA[i], scale, b0);
                float sb = k1ok ? fmaf(sB[i], scale, b1) : -1e30f;
                S0[ks][i] = sa;
                S1[ks][i] = sb;
                mx[i] = fmaxf(mx[i], fmaxf(sa, sb));
            }
        }
#pragma unroll
        for (int i = 0; i < 4; i++) {
            float v = mx[i];
            v = fmaxf(v, __shfl_xor(v, 1));
            v = fmaxf(v, __shfl_xor(v, 2));
            v = fmaxf(v, __shfl_xor(v, 4));
            v = fmaxf(v, __shfl_xor(v, 8));
            mx[i] = v;
        }

        f32x4 O0 = {}, O1 = {};
        float l[4] = {};
#pragma unroll
        for (int ks = 0; ks < 11; ks++) {
            int kbase = ks * 32;
#pragma unroll
            for (int i = 0; i < 4; i++) {
                float pa = exp2_hw(S0[ks][i] - mx[i]);   // col 2*m16   (k=m16)
                float pb = exp2_hw(S1[ks][i] - mx[i]);   // col 2*m16+1 (k=16+m16)
                l[i] += pa + pb;
                *(unsigned int*)&myP[(quad * 4 + i) * PBS + 2 * m16] = pk_bf16(pa, pb);
            }
            s16x4 plo = *(const s16x4*)&myP[m16 * PBS + quad * 8];
            s16x4 phi = *(const s16x4*)&myP[m16 * PBS + quad * 8 + 4];
            s16x8 pf  = __builtin_shufflevector(plo, phi, 0, 1, 2, 3, 4, 5, 6, 7);
            s16x8 vf0 = *(const s16x8*)&Vt[m16 * VP + kbase + quad * 8];
            s16x8 vf1 = *(const s16x8*)&Vt[(16 + m16) * VP + kbase + quad * 8];
            O0 = __builtin_amdgcn_mfma_f32_16x16x32_bf16(pf, vf0, O0, 0, 0, 0);
            O1 = __builtin_amdgcn_mfma_f32_16x16x32_bf16(pf, vf1, O1, 0, 0, 0);
        }
#pragma unroll
        for (int i = 0; i < 4; i++) {
            float v = l[i];
            v += __shfl_xor(v, 1);
            v += __shfl_xor(v, 2);
            v += __shfl_xor(v, 4);
            v += __shfl_xor(v, 8);
            l[i] = v;
        }

        int wd = w >> 4, wh = (w >> 2) & 3, wwi = w & 3;
#pragma unroll
        for (int i = 0; i < 4; i++) {
            int q = qbase + quad * 4 + i;
            if (q < NTOK) {
                float rl = __builtin_amdgcn_rcpf(l[i]);
                int qz = q / 49, qrem = q % 49, qy = qrem / 7, qx = qrem % 7;
                size_t tok = ((size_t)(wd * 7 + qz) * SIDE + (wh * 7 + qy)) * SIDE
                             + (wwi * 7 + qx);
                u16* op = oT + tok * C_DIM + h * HD;
                op[m16]      = f2b(O0[i] * rl);
                op[16 + m16] = f2b(O1[i] * rl);
            }
        }
    }
}

// ---------------------------------------------------------------------------
// Workspace layout unchanged.
// ---------------------------------------------------------------------------
extern "C" void kernel_launch(void* const* d_in, const int* in_sizes, int n_in,
                              void* d_out, int out_size, void* d_ws, size_t ws_size,
                              hipStream_t stream)
{
    const float* skip = (const float*)d_in[0];
    const float* xup  = (const float*)d_in[1];
    const float* ln1g = (const float*)d_in[5];
    const float* ln1b = (const float*)d_in[6];
    const float* kvw  = (const float*)d_in[7];
    const float* kvb  = (const float*)d_in[8];
    const float* rpb  = (const float*)d_in[9];
    const float* pw   = (const float*)d_in[10];
    const float* pb   = (const float*)d_in[11];
    const float* ln2g = (const float*)d_in[12];
    const float* ln2b = (const float*)d_in[13];
    const float* w1   = (const float*)d_in[14];
    const float* b1   = (const float*)d_in[15];
    const float* w2   = (const float*)d_in[16];
    const float* b2   = (const float*)d_in[17];
    float* out = (float*)d_out;

    char* ws = (char*)d_ws;
    const size_t BUFB = (size_t)LTOT * C_DIM * 2;   // 16,859,136 B
    const size_t WTB  = 589824 + 294912 + 1179648 + 1179648;  // 3,244,032 B
    u16* skW = (u16*)(ws);
    u16* qW  = (u16*)(ws + BUFB);
    u16* Kb  = (u16*)(ws + 2 * BUFB);
    u16* Vb  = (u16*)(ws + 3 * BUFB);
    u16* oT  = (u16*)(ws);                  // overlays skW (dead)
    u16* x2  = (u16*)(ws + BUFB);           // overlays qW (dead)
    u16* lnx = (u16*)(ws + 2 * BUFB);       // overlays Kb (dead)
    char* wt = ws + 4 * BUFB;
    u16* kvWt = (u16*)(wt);
    u16* pWt  = (u16*)(wt + 589824);
    u16* w1t  = (u16*)(wt + 589824 + 294912);
    u16* w2t  = (u16*)(wt + 589824 + 294912 + 1179648);
    u16* res  = (u16*)d_out;                // scratch in d_out (dead until mlp2)

    const size_t used = 4 * BUFB + WTB;
    const size_t blkBytes = 128 * 1536 * 2;         // 393,216 B
    size_t tailCap = (ws_size > used) ? (ws_size - used) / blkBytes : 0;
    int chunkBlocks;
    u16* h1c;
    if (tailCap >= 43) {
        chunkBlocks = tailCap < 172 ? (int)tailCap : 172;
        h1c = (u16*)(ws + used);
    } else {
        chunkBlocks = 42;                            // fits in s3 (Vb, dead)
        h1c = (u16*)(ws + 3 * BUFB);
    }

    k_wt<<<dim3(6, 12), 256, 0, stream>>>(kvw, kvWt, 384, 768);
    k_wt<<<dim3(6, 6),  256, 0, stream>>>(pw,  pWt,  384, 384);
    k_wt<<<dim3(6, 24), 256, 0, stream>>>(w1,  w1t,  384, 1536);
    k_wt_pi<<<dim3(24, 6), 256, 0, stream>>>(w2, w2t, 1536, 384);

    k_lnprep<<<LTOT / 4, 256, 0, stream>>>(skip, xup, ln1g, ln1b, skW, qW, res);
    k_gemm_kv<<<dim3(172, 6), 256, 0, stream>>>(skW, kvWt, kvb, Kb, Vb);
    k_attn<<<dim3(NHEAD, NWIN), 512, 0, stream>>>(qW, Kb, Vb, rpb, oT);
    k_gemm_proj<<<dim3(343, 3), 256, 0, stream>>>(oT, pWt, pb, res, x2);
    k_ln2<<<LTOT / 4, 256, 0, stream>>>(x2, ln2g, ln2b, lnx);
    for (int b0 = 0; b0 < 172; b0 += chunkBlocks) {
        int nb = (172 - b0) < chunkBlocks ? (172 - b0) : chunkBlocks;
        int rowOfs = b0 * 128;
        int chunkRows = nb * 128;
        if (rowOfs + chunkRows > LTOT) chunkRows = LTOT - rowOfs;
        int nb64 = (chunkRows + 63) / 64;
        k_gemm_mlp1<<<dim3(nb, 12), 256, 0, stream>>>(lnx, w1t, b1, h1c, rowOfs);
        k_gemm_mlp2<<<dim3(nb64, 3), 256, 0, stream>>>(h1c, w2t, b2, x2, out, rowOfs, chunkRows);
    }
}

// Round 3
// 420.958 us; speedup vs baseline: 1.1732x; 1.1732x over previous
//
#include <hip/hip_runtime.h>
#include <hip/hip_bf16.h>
#include <cstdint>

typedef unsigned short u16;
typedef short s16x8 __attribute__((ext_vector_type(8)));
typedef short s16x4 __attribute__((ext_vector_type(4)));
typedef float f32x4 __attribute__((ext_vector_type(4)));

#define C_DIM 384
#define NHEAD 12
#define HD    32
#define NTOK  343     // tokens per window (7^3)
#define NWIN  64
#define LTOT  21952   // 28^3
#define SIDE  28

__device__ __forceinline__ float u2f(u16 u) {
    return __uint_as_float(((unsigned int)u) << 16);
}
__device__ __forceinline__ u16 f2b(float f) {
    unsigned int u = __float_as_uint(f);
    return (u16)((u + 0x7fffu + ((u >> 16) & 1u)) >> 16);   // RNE
}
__device__ __forceinline__ float exp2_hw(float x) {
    float r;
    asm("v_exp_f32 %0, %1" : "=v"(r) : "v"(x));
    return r;
}
// pack two f32 -> two bf16 (RNE) in one op
__device__ __forceinline__ unsigned int pk_bf16(float lo, float hi) {
    unsigned int r;
    asm("v_cvt_pk_bf16_f32 %0, %1, %2" : "=v"(r) : "v"(lo), "v"(hi));
    return r;
}
// gelu tanh-approx: 0.5x(1+tanh(z)) == x / (1 + 2^(-2z*log2e))
__device__ __forceinline__ float gelu_fast(float x) {
    float e = exp2_hw(-2.3022083f * (x + 0.044715f * x * x * x));
    return x * __builtin_amdgcn_rcpf(1.f + e);
}

// ---------------------------------------------------------------------------
// Weight transpose + f32->bf16: Wt[n][k] = bf16(W[k][n]).  W is KxN row-major.
// ---------------------------------------------------------------------------
__global__ __launch_bounds__(256) void k_wt(
    const float* __restrict__ W, u16* __restrict__ Wt, int K, int N)
{
    __shared__ float T[64][65];
    int k0 = blockIdx.x * 64, n0 = blockIdx.y * 64;
    int t = threadIdx.x;
    int c = t & 63, rg = t >> 6;
#pragma unroll
    for (int i = 0; i < 16; i++) {
        int r = rg * 16 + i;
        T[r][c] = W[(size_t)(k0 + r) * N + n0 + c];
    }
    __syncthreads();
    int k = t & 63, ng = t >> 6;
#pragma unroll
    for (int i = 0; i < 16; i++) {
        int n = ng * 16 + i;
        Wt[(size_t)(n0 + n) * K + k0 + k] = f2b(T[k][n]);
    }
}

// Same, but the k (contraction) index is pi-permuted within each 128-block:
// j = k%128 = ct*16+n  ->  j' = 32*(ct>>1) + 2*n + (ct&1).
// Used for w2 so mlp1 can store h1 in pair-packed column order.
__global__ __launch_bounds__(256) void k_wt_pi(
    const float* __restrict__ W, u16* __restrict__ Wt, int K, int N)
{
    __shared__ float T[64][65];
    int k0 = blockIdx.x * 64, n0 = blockIdx.y * 64;
    int t = threadIdx.x;
    int c = t & 63, rg = t >> 6;
#pragma unroll
    for (int i = 0; i < 16; i++) {
        int r = rg * 16 + i;
        T[r][c] = W[(size_t)(k0 + r) * N + n0 + c];
    }
    __syncthreads();
    int k = t & 63, ng = t >> 6;
    int kg = k0 + k;
    int j = kg & 127, ct = j >> 4, nn = j & 15;
    int kp = (kg & ~127) | ((ct >> 1) << 5) | (nn << 1) | (ct & 1);
#pragma unroll
    for (int i = 0; i < 16; i++) {
        int n = ng * 16 + i;
        Wt[(size_t)(n0 + n) * K + kp] = f2b(T[k][n]);
    }
}

// ---------------------------------------------------------------------------
// Kernel 1: dual LayerNorm + window partition -> bf16; also res = bf16(skip+xup)
// ---------------------------------------------------------------------------
__global__ __launch_bounds__(256) void k_lnprep(
    const float* __restrict__ skip, const float* __restrict__ xup,
    const float* __restrict__ g, const float* __restrict__ bta,
    u16* __restrict__ skW, u16* __restrict__ qW, u16* __restrict__ res)
{
    int t = blockIdx.x * 4 + (threadIdx.x >> 6);
    int lane = threadIdx.x & 63;
    const float* ps = skip + (size_t)t * C_DIM;
    const float* px = xup + (size_t)t * C_DIM;
    float vs[6], vx[6];
    float s1 = 0.f, s2 = 0.f, x1 = 0.f, x2 = 0.f;
#pragma unroll
    for (int j = 0; j < 6; j++) {
        float a = ps[lane + j * 64];
        float b = px[lane + j * 64];
        vs[j] = a; vx[j] = b;
        s1 += a; s2 += a * a; x1 += b; x2 += b * b;
    }
#pragma unroll
    for (int off = 32; off; off >>= 1) {
        s1 += __shfl_xor(s1, off);
        s2 += __shfl_xor(s2, off);
        x1 += __shfl_xor(x1, off);
        x2 += __shfl_xor(x2, off);
    }
    float ms = s1 * (1.f / 384.f), mx = x1 * (1.f / 384.f);
    float rs = rsqrtf(fmaxf(s2 * (1.f / 384.f) - ms * ms, 0.f) + 1e-5f);
    float rx = rsqrtf(fmaxf(x2 * (1.f / 384.f) - mx * mx, 0.f) + 1e-5f);
    int d = t / 784, rem = t % 784, hh = rem / 28, ww = rem % 28;
    int win = (d / 7) * 16 + (hh / 7) * 4 + (ww / 7);
    int n = (d % 7) * 49 + (hh % 7) * 7 + (ww % 7);
    size_t dst = ((size_t)(win * NTOK + n)) * C_DIM + lane;
    size_t td  = (size_t)t * C_DIM + lane;
#pragma unroll
    for (int j = 0; j < 6; j++) {
        int c = lane + j * 64;
        float gg = g[c], bb = bta[c];
        skW[dst + j * 64] = f2b((vs[j] - ms) * rs * gg + bb);
        qW[dst + j * 64]  = f2b((vx[j] - mx) * rx * gg + bb);
        res[td + j * 64]  = f2b(vs[j] + vx[j]);
    }
}

// ---------------------------------------------------------------------------
// Kernel 5: LayerNorm of x2 (bf16) -> lnx (bf16).
// ---------------------------------------------------------------------------
__global__ __launch_bounds__(256) void k_ln2(
    const u16* __restrict__ x2, const float* __restrict__ g,
    const float* __restrict__ bta, u16* __restrict__ lnx)
{
    int t = blockIdx.x * 4 + (threadIdx.x >> 6);
    int lane = threadIdx.x & 63;
    const u16* p = x2 + (size_t)t * C_DIM;
    float v[6];
    float s1 = 0.f, s2 = 0.f;
#pragma unroll
    for (int j = 0; j < 6; j++) {
        float a = u2f(p[lane + j * 64]);
        v[j] = a; s1 += a; s2 += a * a;
    }
#pragma unroll
    for (int off = 32; off; off >>= 1) {
        s1 += __shfl_xor(s1, off);
        s2 += __shfl_xor(s2, off);
    }
    float m = s1 * (1.f / 384.f);
    float r = rsqrtf(fmaxf(s2 * (1.f / 384.f) - m * m, 0.f) + 1e-5f);
    size_t dst = (size_t)t * C_DIM + lane;
#pragma unroll
    for (int j = 0; j < 6; j++) {
        int c = lane + j * 64;
        lnx[dst + j * 64] = f2b((v[j] - m) * r * g[c] + bta[c]);
    }
}

// ---------------------------------------------------------------------------
// 128x128 MFMA GEMM core (unchanged).
// ---------------------------------------------------------------------------
#define BPAD 40   // LDS row stride in u16 (32 data + 8 pad; 2-way banks)

__device__ __forceinline__ void gemm128(
    const u16* __restrict__ A, const u16* __restrict__ Bt, int K, int M,
    int rowBase, int colBase, int tid,
    u16 (*As)[BPAD], u16 (*Bs)[BPAD], f32x4 acc[2][8])
{
    const int sr  = tid >> 2;
    const int scg = (tid & 3) << 3;
    const int lane = tid & 63, wv = tid >> 6;
    const int m16 = lane & 15, quad = lane >> 4;

    int ra0 = min(rowBase + sr, M - 1);
    int ra1 = min(rowBase + 64 + sr, M - 1);
    const u16* pa0 = A + (size_t)ra0 * K + scg;
    const u16* pa1 = A + (size_t)ra1 * K + scg;
    const u16* pb0 = Bt + (size_t)(colBase + sr) * K + scg;
    const u16* pb1 = Bt + (size_t)(colBase + 64 + sr) * K + scg;

    uint4 a0 = *(const uint4*)pa0, a1 = *(const uint4*)pa1;
    uint4 b0 = *(const uint4*)pb0, b1 = *(const uint4*)pb1;

    for (int kk = 0; kk < K; kk += 32) {
        *(uint4*)&As[sr][scg]      = a0;
        *(uint4*)&As[64 + sr][scg] = a1;
        *(uint4*)&Bs[sr][scg]      = b0;
        *(uint4*)&Bs[64 + sr][scg] = b1;
        __syncthreads();
        if (kk + 32 < K) {
            a0 = *(const uint4*)(pa0 + kk + 32);
            a1 = *(const uint4*)(pa1 + kk + 32);
            b0 = *(const uint4*)(pb0 + kk + 32);
            b1 = *(const uint4*)(pb1 + kk + 32);
        }
        s16x8 af0 = *(const s16x8*)&As[wv * 32 + m16][quad * 8];
        s16x8 af1 = *(const s16x8*)&As[wv * 32 + 16 + m16][quad * 8];
#pragma unroll
        for (int c = 0; c < 8; c++) {
            s16x8 bf = *(const s16x8*)&Bs[c * 16 + m16][quad * 8];
            acc[0][c] = __builtin_amdgcn_mfma_f32_16x16x32_bf16(af0, bf, acc[0][c], 0, 0, 0);
            acc[1][c] = __builtin_amdgcn_mfma_f32_16x16x32_bf16(af1, bf, acc[1][c], 0, 0, 0);
        }
        __syncthreads();
    }
}

// ---------------------------------------------------------------------------
// 64x128 MFMA GEMM core with 2-deep register prefetch (unchanged).
// ---------------------------------------------------------------------------
__device__ __forceinline__ void gemm64_d2(
    const u16* __restrict__ A, const u16* __restrict__ Bt, int K, int M,
    int rowBase, int colBase, int tid,
    u16 (*As)[BPAD], u16 (*Bs)[BPAD], f32x4 acc[8])
{
    const int sr  = tid >> 2;
    const int scg = (tid & 3) << 3;
    const int lane = tid & 63, wv = tid >> 6;
    const int m16 = lane & 15, quad = lane >> 4;

    int ra = min(rowBase + sr, M - 1);
    const u16* pa  = A + (size_t)ra * K + scg;
    const u16* pb0 = Bt + (size_t)(colBase + sr) * K + scg;
    const u16* pb1 = Bt + (size_t)(colBase + 64 + sr) * K + scg;

    uint4 a0  = *(const uint4*)pa;
    uint4 b00 = *(const uint4*)pb0;
    uint4 b01 = *(const uint4*)pb1;
    uint4 a1  = *(const uint4*)(pa + 32);
    uint4 b10 = *(const uint4*)(pb0 + 32);
    uint4 b11 = *(const uint4*)(pb1 + 32);

    for (int kk = 0; kk < K; kk += 64) {
        *(uint4*)&As[sr][scg]      = a0;
        *(uint4*)&Bs[sr][scg]      = b00;
        *(uint4*)&Bs[64 + sr][scg] = b01;
        __syncthreads();
        if (kk + 64 < K) {
            a0  = *(const uint4*)(pa  + kk + 64);
            b00 = *(const uint4*)(pb0 + kk + 64);
            b01 = *(const uint4*)(pb1 + kk + 64);
        }
        {
            s16x8 af = *(const s16x8*)&As[wv * 16 + m16][quad * 8];
#pragma unroll
            for (int c = 0; c < 8; c++) {
                s16x8 bf = *(const s16x8*)&Bs[c * 16 + m16][quad * 8];
                acc[c] = __builtin_amdgcn_mfma_f32_16x16x32_bf16(af, bf, acc[c], 0, 0, 0);
            }
        }
        __syncthreads();
        *(uint4*)&As[sr][scg]      = a1;
        *(uint4*)&Bs[sr][scg]      = b10;
        *(uint4*)&Bs[64 + sr][scg] = b11;
        __syncthreads();
        if (kk + 96 < K) {
            a1  = *(const uint4*)(pa  + kk + 96);
            b10 = *(const uint4*)(pb0 + kk + 96);
            b11 = *(const uint4*)(pb1 + kk + 96);
        }
        {
            s16x8 af = *(const s16x8*)&As[wv * 16 + m16][quad * 8];
#pragma unroll
            for (int c = 0; c < 8; c++) {
                s16x8 bf = *(const s16x8*)&Bs[c * 16 + m16][quad * 8];
                acc[c] = __builtin_amdgcn_mfma_f32_16x16x32_bf16(af, bf, acc[c], 0, 0, 0);
            }
        }
        __syncthreads();
    }
}

#define EPI_SETUP \
    int lane = tid & 63, wv = tid >> 6, quad = lane >> 4, n16 = lane & 15;

// KV projection (K=384, N=768): scatter to K/V (w,head,n,d) bf16.
__global__ __launch_bounds__(256) void k_gemm_kv(
    const u16* __restrict__ A, const u16* __restrict__ Wt, const float* __restrict__ bias,
    u16* __restrict__ Kb, u16* __restrict__ Vb)
{
    __shared__ __align__(16) u16 As[128][BPAD];
    __shared__ __align__(16) u16 Bs[128][BPAD];
    f32x4 acc[2][8] = {};
    int tid = threadIdx.x;
    int rowBase = blockIdx.x * 128, colBase = blockIdx.y * 128;
    gemm128(A, Wt, 384, LTOT, rowBase, colBase, tid, As, Bs, acc);
    EPI_SETUP
#pragma unroll
    for (int c = 0; c < 8; c++) {
        int col = colBase + c * 16 + n16;
        float bcol = bias[col];
        int isv = col >= 384;
        int remc = col - (isv ? 384 : 0);
        int hh = remc >> 5, dd = remc & 31;
#pragma unroll
        for (int rt = 0; rt < 2; rt++)
#pragma unroll
        for (int reg = 0; reg < 4; reg++) {
            int r = rowBase + wv * 32 + rt * 16 + quad * 4 + reg;
            if (r < LTOT) {
                int w = r / NTOK, nn = r % NTOK;
                size_t dst = ((size_t)((w * NHEAD + hh) * NTOK + nn)) * HD + dd;
                (isv ? Vb : Kb)[dst] = f2b(acc[rt][c][reg] + bcol);
            }
        }
    }
}

// Output projection (K=384, N=384) + bias + residual res (bf16) -> x2 bf16.
__global__ __launch_bounds__(256) void k_gemm_proj(
    const u16* __restrict__ A, const u16* __restrict__ Wt, const float* __restrict__ bias,
    const u16* __restrict__ res, u16* __restrict__ x2)
{
    __shared__ __align__(16) u16 As[64][BPAD];
    __shared__ __align__(16) u16 Bs[128][BPAD];
    f32x4 acc[8] = {};
    int tid = threadIdx.x;
    int rowBase = blockIdx.x * 64, colBase = blockIdx.y * 128;
    gemm64_d2(A, Wt, 384, LTOT, rowBase, colBase, tid, As, Bs, acc);
    EPI_SETUP
#pragma unroll
    for (int c = 0; c < 8; c++) {
        int col = colBase + c * 16 + n16;
        float bcol = bias[col];
#pragma unroll
        for (int reg = 0; reg < 4; reg++) {
            int r = rowBase + wv * 16 + quad * 4 + reg;
            if (r < LTOT) {
                size_t idx = (size_t)r * C_DIM + col;
                x2[idx] = f2b(acc[c][reg] + bcol + u2f(res[idx]));
            }
        }
    }
}

// MLP1 (K=384, N=1536) + bias + gelu -> h1 chunk bf16, pair-packed columns:
// within each 128-col block, cols (32p+n, 32p+16+n) -> packed u32 at 32p+2n.
// w2t is permuted identically (k_wt_pi) so mlp2 is unchanged.
__global__ __launch_bounds__(256) void k_gemm_mlp1(
    const u16* __restrict__ A, const u16* __restrict__ Wt, const float* __restrict__ bias,
    u16* __restrict__ h1c, int rowOfs)
{
    __shared__ __align__(16) u16 As[128][BPAD];
    __shared__ __align__(16) u16 Bs[128][BPAD];
    f32x4 acc[2][8] = {};
    int tid = threadIdx.x;
    int rowBase = rowOfs + blockIdx.x * 128, colBase = blockIdx.y * 128;
    gemm128(A, Wt, 384, LTOT, rowBase, colBase, tid, As, Bs, acc);
    EPI_SETUP
#pragma unroll
    for (int p = 0; p < 4; p++) {
        int col0 = colBase + p * 32 + n16;    // ct = 2p
        int col1 = col0 + 16;                 // ct = 2p+1
        float bc0 = bias[col0], bc1 = bias[col1];
        int dcol = colBase + p * 32 + 2 * n16;
#pragma unroll
        for (int rt = 0; rt < 2; rt++)
#pragma unroll
        for (int reg = 0; reg < 4; reg++) {
            int r = rowBase + wv * 32 + rt * 16 + quad * 4 + reg;
            if (r < LTOT) {
                size_t rl = (size_t)(r - rowOfs);
                float v0 = gelu_fast(acc[rt][2 * p][reg] + bc0);
                float v1 = gelu_fast(acc[rt][2 * p + 1][reg] + bc1);
                *(unsigned int*)&h1c[rl * 1536 + dcol] = pk_bf16(v0, v1);
            }
        }
    }
}

// MLP2 (K=1536 permuted, N=384) + bias + residual x2 (bf16) -> out f32 (final).
__global__ __launch_bounds__(256) void k_gemm_mlp2(
    const u16* __restrict__ A, const u16* __restrict__ Wt, const float* __restrict__ bias,
    const u16* __restrict__ x2, float* __restrict__ out, int rowOfs, int chunkRows)
{
    __shared__ __align__(16) u16 As[64][BPAD];
    __shared__ __align__(16) u16 Bs[128][BPAD];
    f32x4 acc[8] = {};
    int tid = threadIdx.x;
    int rowBase = blockIdx.x * 64, colBase = blockIdx.y * 128;   // local rows
    gemm64_d2(A, Wt, 1536, chunkRows, rowBase, colBase, tid, As, Bs, acc);
    EPI_SETUP
#pragma unroll
    for (int c = 0; c < 8; c++) {
        int col = colBase + c * 16 + n16;
        float bcol = bias[col];
#pragma unroll
        for (int reg = 0; reg < 4; reg++) {
            int rl = rowBase + wv * 16 + quad * 4 + reg;
            int rg = rowOfs + rl;
            if (rl < chunkRows && rg < LTOT) {
                size_t idx = (size_t)rg * C_DIM + col;
                out[idx] = acc[c][reg] + bcol + u2f(x2[idx]);
            }
        }
    }
}

// ---------------------------------------------------------------------------
// Kernel 3: MFMA flash attention. One 256-thread block (4 waves) per
// (head, window); K/V staged ONCE; each wave owns ~5-6 of 22 q-tiles.
// launch_bounds(256,2) keeps the per-thread register budget at round-1's
// proven no-spill level (S0/S1 state fits in VGPR+AGPR).
// Softmax in log2 domain (scale & bias pre-multiplied by log2e) -> bare
// v_exp_f32. P stored pair-packed (col c = 2*(k&15)+(k>>4)) via
// v_cvt_pk_bf16_f32 + ds_write_b32; V staged with the identical column
// permutation so P.V is unchanged.
// LDS: Ks 28160 + Vt 23040 + rp16 4400 + code 704 + Pb 4608 = 60912 B
//  -> 2 blocks/CU.
// ---------------------------------------------------------------------------
#define KP  40     // Ks row stride (u16), 80 B: 16B-aligned b128 rows
#define VP  360    // Vt row stride (u16), 720 B: 16B-aligned, 8-bank spread
#define PBS 36     // Pb row stride (u16), 72 B: 8B-aligned (read as 2xb64)

__global__ __launch_bounds__(256, 2) void k_attn(
    const u16* __restrict__ qW, const u16* __restrict__ Kb, const u16* __restrict__ Vb,
    const float* __restrict__ rpb, u16* __restrict__ oT)
{
    __shared__ __align__(16) u16 Ks[352 * KP];       // 28160 B
    __shared__ __align__(16) u16 Vt[32 * VP];        // 23040 B
    __shared__ __align__(16) u16 rp16[2200];         //  4400 B
    __shared__ __align__(16) u16 code[352];          //   704 B
    __shared__ __align__(16) u16 Pb[4 * 16 * PBS];   //  4608 B

    const int h = blockIdx.x, w = blockIdx.y;
    const int tid = threadIdx.x;
    const int lane = tid & 63, wv = tid >> 6;
    const int m16 = lane & 15, quad = lane >> 4;
    const size_t base = ((size_t)(w * NHEAD + h)) * NTOK * HD;

    // K: rows = tokens (zero-padded to 352), 16B chunks.
    for (int t = tid; t < 1408; t += 256) {
        int r = t >> 2, c = (t & 3) << 3;
        uint4 u = make_uint4(0, 0, 0, 0);
        if (r < NTOK) u = *(const uint4*)(Kb + base + r * HD + c);
        *(uint4*)&Ks[r * KP + c] = u;
    }
    // V transposed [d][col], col = 32*kb + 2*j (token kb*32+j) | +1 (token +16).
    for (int t = tid; t < 704; t += 256) {
        int dg = t / 176, rem = t - dg * 176;
        int kb = rem >> 4, j = rem & 15;
        int n0 = kb * 32 + j, n1 = n0 + 16;
        uint4 uA = make_uint4(0, 0, 0, 0), uB = make_uint4(0, 0, 0, 0);
        if (n0 < NTOK) uA = *(const uint4*)(Vb + base + n0 * HD + dg * 8);
        if (n1 < NTOK) uB = *(const uint4*)(Vb + base + n1 * HD + dg * 8);
        int d0 = dg * 8, colu = kb * 32 + 2 * j;
        unsigned int pk0 = (uA.x & 0xffffu) | (uB.x << 16);
        unsigned int pk1 = (uA.x >> 16)     | (uB.x & 0xffff0000u);
        unsigned int pk2 = (uA.y & 0xffffu) | (uB.y << 16);
        unsigned int pk3 = (uA.y >> 16)     | (uB.y & 0xffff0000u);
        unsigned int pk4 = (uA.z & 0xffffu) | (uB.z << 16);
        unsigned int pk5 = (uA.z >> 16)     | (uB.z & 0xffff0000u);
        unsigned int pk6 = (uA.w & 0xffffu) | (uB.w << 16);
        unsigned int pk7 = (uA.w >> 16)     | (uB.w & 0xffff0000u);
        *(unsigned int*)&Vt[(d0 + 0) * VP + colu] = pk0;
        *(unsigned int*)&Vt[(d0 + 1) * VP + colu] = pk1;
        *(unsigned int*)&Vt[(d0 + 2) * VP + colu] = pk2;
        *(unsigned int*)&Vt[(d0 + 3) * VP + colu] = pk3;
        *(unsigned int*)&Vt[(d0 + 4) * VP + colu] = pk4;
        *(unsigned int*)&Vt[(d0 + 5) * VP + colu] = pk5;
        *(unsigned int*)&Vt[(d0 + 6) * VP + colu] = pk6;
        *(unsigned int*)&Vt[(d0 + 7) * VP + colu] = pk7;
    }
    // bias table in log2 units
    for (int t = tid; t < 2200; t += 256)
        rp16[t] = (t < 2197) ? f2b(rpb[t * NHEAD + h] * 1.4426950408889634f) : (u16)0;
    for (int t = tid; t < 352; t += 256) {
        int z = t / 49, rem = t % 49, y = rem / 7, x = rem % 7;
        code[t] = (t < NTOK) ? (u16)(z * 169 + y * 13 + x) : (u16)1098;
    }
    __syncthreads();

    const float scale = 0.2550348772f;  // (1/sqrt(32)) * log2(e)
    u16* myP = Pb + wv * 16 * PBS;

    for (int qt = wv; qt < 22; qt += 4) {
        int qbase = qt * 16;
        int qrow = min(qbase + m16, NTOK - 1);
        s16x8 qf = *(const s16x8*)(qW + ((size_t)(w * NTOK + qrow)) * C_DIM
                                       + h * HD + quad * 8);
        int qcv[4];
#pragma unroll
        for (int i = 0; i < 4; i++) qcv[i] = code[qbase + quad * 4 + i];

        f32x4 S0[11], S1[11];
        float mx[4] = {-1e30f, -1e30f, -1e30f, -1e30f};

#pragma unroll
        for (int ks = 0; ks < 11; ks++) {
            int kbase = ks * 32;
            int kt0 = kbase + m16, kt1 = kt0 + 16;
            s16x8 kf0 = *(const s16x8*)&Ks[kt0 * KP + quad * 8];
            s16x8 kf1 = *(const s16x8*)&Ks[kt1 * KP + quad * 8];
            f32x4 z = {0.f, 0.f, 0.f, 0.f};
            f32x4 sA = __builtin_amdgcn_mfma_f32_16x16x32_bf16(qf, kf0, z, 0, 0, 0);
            f32x4 sB = __builtin_amdgcn_mfma_f32_16x16x32_bf16(qf, kf1, z, 0, 0, 0);
            int kc0 = code[kt0], kc1 = code[kt1];
            bool k1ok = (ks < 10) || (kt1 < NTOK);
#pragma unroll
            for (int i = 0; i < 4; i++) {
                float b0 = u2f(rp16[qcv[i] - kc0 + 1098]);
                float b1 = u2f(rp16[qcv[i] - kc1 + 1098]);
                float sa = fmaf(sA[i], scale, b0);
                float sb = k1ok ? fmaf(sB[i], scale, b1) : -1e30f;
                S0[ks][i] = sa;
                S1[ks][i] = sb;
                mx[i] = fmaxf(mx[i], fmaxf(sa, sb));
            }
        }
#pragma unroll
        for (int i = 0; i < 4; i++) {
            float v = mx[i];
            v = fmaxf(v, __shfl_xor(v, 1));
            v = fmaxf(v, __shfl_xor(v, 2));
            v = fmaxf(v, __shfl_xor(v, 4));
            v = fmaxf(v, __shfl_xor(v, 8));
            mx[i] = v;
        }

        f32x4 O0 = {}, O1 = {};
        float l[4] = {};
#pragma unroll
        for (int ks = 0; ks < 11; ks++) {
            int kbase = ks * 32;
#pragma unroll
            for (int i = 0; i < 4; i++) {
                float pa = exp2_hw(S0[ks][i] - mx[i]);   // col 2*m16   (k=m16)
                float pb = exp2_hw(S1[ks][i] - mx[i]);   // col 2*m16+1 (k=16+m16)
                l[i] += pa + pb;
                *(unsigned int*)&myP[(quad * 4 + i) * PBS + 2 * m16] = pk_bf16(pa, pb);
            }
            s16x4 plo = *(const s16x4*)&myP[m16 * PBS + quad * 8];
            s16x4 phi = *(const s16x4*)&myP[m16 * PBS + quad * 8 + 4];
            s16x8 pf  = __builtin_shufflevector(plo, phi, 0, 1, 2, 3, 4, 5, 6, 7);
            s16x8 vf0 = *(const s16x8*)&Vt[m16 * VP + kbase + quad * 8];
            s16x8 vf1 = *(const s16x8*)&Vt[(16 + m16) * VP + kbase + quad * 8];
            O0 = __builtin_amdgcn_mfma_f32_16x16x32_bf16(pf, vf0, O0, 0, 0, 0);
            O1 = __builtin_amdgcn_mfma_f32_16x16x32_bf16(pf, vf1, O1, 0, 0, 0);
        }
#pragma unroll
        for (int i = 0; i < 4; i++) {
            float v = l[i];
            v += __shfl_xor(v, 1);
            v += __shfl_xor(v, 2);
            v += __shfl_xor(v, 4);
            v += __shfl_xor(v, 8);
            l[i] = v;
        }

        int wd = w >> 4, wh = (w >> 2) & 3, wwi = w & 3;
#pragma unroll
        for (int i = 0; i < 4; i++) {
            int q = qbase + quad * 4 + i;
            if (q < NTOK) {
                float rl = __builtin_amdgcn_rcpf(l[i]);
                int qz = q / 49, qrem = q % 49, qy = qrem / 7, qx = qrem % 7;
                size_t tok = ((size_t)(wd * 7 + qz) * SIDE + (wh * 7 + qy)) * SIDE
                             + (wwi * 7 + qx);
                u16* op = oT + tok * C_DIM + h * HD;
                op[m16]      = f2b(O0[i] * rl);
                op[16 + m16] = f2b(O1[i] * rl);
            }
        }
    }
}

// ---------------------------------------------------------------------------
// Workspace layout unchanged.
// ---------------------------------------------------------------------------
extern "C" void kernel_launch(void* const* d_in, const int* in_sizes, int n_in,
                              void* d_out, int out_size, void* d_ws, size_t ws_size,
                              hipStream_t stream)
{
    const float* skip = (const float*)d_in[0];
    const float* xup  = (const float*)d_in[1];
    const float* ln1g = (const float*)d_in[5];
    const float* ln1b = (const float*)d_in[6];
    const float* kvw  = (const float*)d_in[7];
    const float* kvb  = (const float*)d_in[8];
    const float* rpb  = (const float*)d_in[9];
    const float* pw   = (const float*)d_in[10];
    const float* pb   = (const float*)d_in[11];
    const float* ln2g = (const float*)d_in[12];
    const float* ln2b = (const float*)d_in[13];
    const float* w1   = (const float*)d_in[14];
    const float* b1   = (const float*)d_in[15];
    const float* w2   = (const float*)d_in[16];
    const float* b2   = (const float*)d_in[17];
    float* out = (float*)d_out;

    char* ws = (char*)d_ws;
    const size_t BUFB = (size_t)LTOT * C_DIM * 2;   // 16,859,136 B
    const size_t WTB  = 589824 + 294912 + 1179648 + 1179648;  // 3,244,032 B
    u16* skW = (u16*)(ws);
    u16* qW  = (u16*)(ws + BUFB);
    u16* Kb  = (u16*)(ws + 2 * BUFB);
    u16* Vb  = (u16*)(ws + 3 * BUFB);
    u16* oT  = (u16*)(ws);                  // overlays skW (dead)
    u16* x2  = (u16*)(ws + BUFB);           // overlays qW (dead)
    u16* lnx = (u16*)(ws + 2 * BUFB);       // overlays Kb (dead)
    char* wt = ws + 4 * BUFB;
    u16* kvWt = (u16*)(wt);
    u16* pWt  = (u16*)(wt + 589824);
    u16* w1t  = (u16*)(wt + 589824 + 294912);
    u16* w2t  = (u16*)(wt + 589824 + 294912 + 1179648);
    u16* res  = (u16*)d_out;                // scratch in d_out (dead until mlp2)

    const size_t used = 4 * BUFB + WTB;
    const size_t blkBytes = 128 * 1536 * 2;         // 393,216 B
    size_t tailCap = (ws_size > used) ? (ws_size - used) / blkBytes : 0;
    int chunkBlocks;
    u16* h1c;
    if (tailCap >= 43) {
        chunkBlocks = tailCap < 172 ? (int)tailCap : 172;
        h1c = (u16*)(ws + used);
    } else {
        chunkBlocks = 42;                            // fits in s3 (Vb, dead)
        h1c = (u16*)(ws + 3 * BUFB);
    }

    k_wt<<<dim3(6, 12), 256, 0, stream>>>(kvw, kvWt, 384, 768);
    k_wt<<<dim3(6, 6),  256, 0, stream>>>(pw,  pWt,  384, 384);
    k_wt<<<dim3(6, 24), 256, 0, stream>>>(w1,  w1t,  384, 1536);
    k_wt_pi<<<dim3(24, 6), 256, 0, stream>>>(w2, w2t, 1536, 384);

    k_lnprep<<<LTOT / 4, 256, 0, stream>>>(skip, xup, ln1g, ln1b, skW, qW, res);
    k_gemm_kv<<<dim3(172, 6), 256, 0, stream>>>(skW, kvWt, kvb, Kb, Vb);
    k_attn<<<dim3(NHEAD, NWIN), 256, 0, stream>>>(qW, Kb, Vb, rpb, oT);
    k_gemm_proj<<<dim3(343, 3), 256, 0, stream>>>(oT, pWt, pb, res, x2);
    k_ln2<<<LTOT / 4, 256, 0, stream>>>(x2, ln2g, ln2b, lnx);
    for (int b0 = 0; b0 < 172; b0 += chunkBlocks) {
        int nb = (172 - b0) < chunkBlocks ? (172 - b0) : chunkBlocks;
        int rowOfs = b0 * 128;
        int chunkRows = nb * 128;
        if (rowOfs + chunkRows > LTOT) chunkRows = LTOT - rowOfs;
        int nb64 = (chunkRows + 63) / 64;
        k_gemm_mlp1<<<dim3(nb, 12), 256, 0, stream>>>(lnx, w1t, b1, h1c, rowOfs);
        k_gemm_mlp2<<<dim3(nb64, 3), 256, 0, stream>>>(h1c, w2t, b2, x2, out, rowOfs, chunkRows);
    }
}